// Round 1
// baseline (185.739 us; speedup 1.0000x reference)
//
#include <hip/hip_runtime.h>
#include <math.h>

#define BLOCK 256
#define CHUNK 1024

// Rounding-exact helpers: prevent FMA contraction so we match numpy's
// mul-then-add rounding for norms and the final (a2+b2) add.
__device__ __forceinline__ float mul_rn(float a, float b) {
#pragma clang fp contract(off)
    return a * b;
}
__device__ __forceinline__ float add_rn(float a, float b) {
#pragma clang fp contract(off)
    return a + b;
}
__device__ __forceinline__ float sumsq3(float x, float y, float z) {
    // numpy: sum(a*a, axis=-1) -> ((x*x + y*y) + z*z), each op rounded
    return add_rn(add_rn(mul_rn(x, x), mul_rn(y, y)), mul_rn(z, z));
}

// Kernel 1: each thread = one query, scanning one slice of refs.
// Maintains top-3 smallest sq = (an + bn) - 2*dot with index tie-break
// (strict <  => earlier index wins, matching lax.top_k).
__global__ __launch_bounds__(BLOCK) void knn_slice_kernel(
    const float* __restrict__ q, const float* __restrict__ r,
    float* __restrict__ cand, int M, int refsPerSlice)
{
    __shared__ float4 smem[CHUNK];
    const int qi = blockIdx.x * BLOCK + threadIdx.x;
    const int s  = blockIdx.y;
    const int start = s * refsPerSlice;

    const float a0 = q[qi * 3 + 0];
    const float a1 = q[qi * 3 + 1];
    const float a2 = q[qi * 3 + 2];
    const float an = sumsq3(a0, a1, a2);

    float d0 = __builtin_inff(), d1 = __builtin_inff(), d2 = __builtin_inff();
    int   i0 = 0, i1 = 0, i2 = 0;

    for (int coff = 0; coff < refsPerSlice; coff += CHUNK) {
        const int cnt = min(CHUNK, refsPerSlice - coff);
        __syncthreads();
        for (int j = threadIdx.x; j < cnt; j += BLOCK) {
            const int rj = start + coff + j;
            const float b0 = r[3 * rj + 0];
            const float b1 = r[3 * rj + 1];
            const float b2 = r[3 * rj + 2];
            smem[j] = make_float4(b0, b1, b2, sumsq3(b0, b1, b2));
        }
        __syncthreads();
        const int base = start + coff;
#pragma unroll 4
        for (int j = 0; j < cnt; ++j) {
            const float4 b = smem[j];
            // dot = fma(a2,b2, fma(a1,b1, round(a0*b0)))  (BLAS k-order)
            const float dot = __builtin_fmaf(a2, b.z,
                              __builtin_fmaf(a1, b.y, mul_rn(a0, b.x)));
            const float s2 = add_rn(an, b.w);
            // (an+bn) - 2*dot : 2*dot is exact, so single-rounded fma matches
            const float sq = __builtin_fmaf(-2.0f, dot, s2);
            const int idx = base + j;
            const bool c2c = sq < d2;
            const bool c1c = sq < d1;
            const bool c0c = sq < d0;
            d2 = c1c ? d1 : (c2c ? sq  : d2);
            i2 = c1c ? i1 : (c2c ? idx : i2);
            d1 = c0c ? d0 : (c1c ? sq  : d1);
            i1 = c0c ? i0 : (c1c ? idx : i1);
            d0 = c0c ? sq  : d0;
            i0 = c0c ? idx : i0;
        }
    }

    float* outp = cand + ((size_t)qi * gridDim.y + s) * 6;
    outp[0] = d0; outp[1] = __int_as_float(i0);
    outp[2] = d1; outp[3] = __int_as_float(i1);
    outp[4] = d2; outp[5] = __int_as_float(i2);
}

// Kernel 2: merge per-slice top-3 candidates, compute weights + output.
__global__ __launch_bounds__(BLOCK) void knn_merge_kernel(
    const float* __restrict__ cand, const float* __restrict__ flow,
    float* __restrict__ out, int slices)
{
    const int qi = blockIdx.x * BLOCK + threadIdx.x;
    float d0 = __builtin_inff(), d1 = __builtin_inff(), d2 = __builtin_inff();
    int   i0 = 0, i1 = 0, i2 = 0;

    const float* c = cand + (size_t)qi * slices * 6;
    const int total = slices * 3;
    for (int t = 0; t < total; ++t) {
        const float sq  = c[2 * t];
        const int   idx = __float_as_int(c[2 * t + 1]);
        const bool c2c = sq < d2;
        const bool c1c = sq < d1;
        const bool c0c = sq < d0;
        d2 = c1c ? d1 : (c2c ? sq  : d2);
        i2 = c1c ? i1 : (c2c ? idx : i2);
        d1 = c0c ? d0 : (c1c ? sq  : d1);
        i1 = c0c ? i0 : (c1c ? idx : i1);
        d0 = c0c ? sq  : d0;
        i0 = c0c ? idx : i0;
    }

    // dist = sqrt(max(sq, 1e-12)); w = 1/(dist + 1e-8); normalize
    const float t0 = sqrtf(fmaxf(d0, 1e-12f));
    const float t1 = sqrtf(fmaxf(d1, 1e-12f));
    const float t2 = sqrtf(fmaxf(d2, 1e-12f));
    const float w0r = 1.0f / add_rn(t0, 1e-8f);
    const float w1r = 1.0f / add_rn(t1, 1e-8f);
    const float w2r = 1.0f / add_rn(t2, 1e-8f);
    const float wsum = add_rn(add_rn(w0r, w1r), w2r);
    const float w0 = w0r / wsum;
    const float w1 = w1r / wsum;
    const float w2 = w2r / wsum;

    const float f00 = flow[3 * i0 + 0], f01 = flow[3 * i0 + 1], f02 = flow[3 * i0 + 2];
    const float f10 = flow[3 * i1 + 0], f11 = flow[3 * i1 + 1], f12 = flow[3 * i1 + 2];
    const float f20 = flow[3 * i2 + 0], f21 = flow[3 * i2 + 1], f22 = flow[3 * i2 + 2];

    // sum over k sequential: ((w0*f0 + w1*f1) + w2*f2), each op rounded
    out[qi * 3 + 0] = add_rn(add_rn(mul_rn(w0, f00), mul_rn(w1, f10)), mul_rn(w2, f20));
    out[qi * 3 + 1] = add_rn(add_rn(mul_rn(w0, f01), mul_rn(w1, f11)), mul_rn(w2, f21));
    out[qi * 3 + 2] = add_rn(add_rn(mul_rn(w0, f02), mul_rn(w1, f12)), mul_rn(w2, f22));
}

extern "C" void kernel_launch(void* const* d_in, const int* in_sizes, int n_in,
                              void* d_out, int out_size, void* d_ws, size_t ws_size,
                              hipStream_t stream) {
    const float* q    = (const float*)d_in[0];
    const float* r    = (const float*)d_in[1];
    const float* flow = (const float*)d_in[2];
    // d_in[3] is k (==3), hard-coded below.

    const int N = in_sizes[0] / 3;
    const int M = in_sizes[1] / 3;

    int slices = 16;
    while (slices > 1 && (size_t)N * slices * 6 * sizeof(float) > ws_size) slices >>= 1;
    const int refsPerSlice = M / slices;

    dim3 grid1(N / BLOCK, slices);
    knn_slice_kernel<<<grid1, BLOCK, 0, stream>>>(q, r, (float*)d_ws, M, refsPerSlice);
    knn_merge_kernel<<<N / BLOCK, BLOCK, 0, stream>>>((const float*)d_ws, flow,
                                                      (float*)d_out, slices);
}